// Round 6
// baseline (39.917 us; speedup 1.0000x reference)
//
#include <hip/hip_runtime.h>

typedef float  f32x4 __attribute__((ext_vector_type(4)));
typedef short  s16x8 __attribute__((ext_vector_type(8)));
typedef _Float16 h2 __attribute__((ext_vector_type(2)));
typedef unsigned short u16;

#define N_DIMS 1024
#define N_OSC  352
#define BATCH  4096
#define EPSV   1e-6f
#define INV2PI 0.15915494309189535f

// ---------------- fused GEMM: C[4096][704] = x @ [Wp;Wa]^T, f32 in, bf16 MFMA ----------------
// BM=BN=BK=64, 4 waves (2x2), wave tile 32x32 via 16x16x32 MFMA acc[2][2].
// Staging: reg-staged f32 (8x float4/thread) -> v_cvt_pk_bf16_f32 -> 4x ds_write_b128
// into T2-swizzled double-buffered LDS (slot q at q^(row&7) within each 128B row).
// T14 split: loads for kt+2 issued after the cvt+write of kt+1 -> latency hides
// under compute(kt) + barrier. XCD-swizzled block id (704 = 8 x 88, bijective).
__device__ __forceinline__ void cvt_wr(const f32x4* rx, u16* b0, u16* b1){
  unsigned v0,v1,v2,v3,v4,v5,v6,v7;
  asm("v_cvt_pk_bf16_f32 %0, %1, %2" : "=v"(v0) : "v"(rx[0][0]), "v"(rx[0][1]));
  asm("v_cvt_pk_bf16_f32 %0, %1, %2" : "=v"(v1) : "v"(rx[0][2]), "v"(rx[0][3]));
  asm("v_cvt_pk_bf16_f32 %0, %1, %2" : "=v"(v2) : "v"(rx[1][0]), "v"(rx[1][1]));
  asm("v_cvt_pk_bf16_f32 %0, %1, %2" : "=v"(v3) : "v"(rx[1][2]), "v"(rx[1][3]));
  asm("v_cvt_pk_bf16_f32 %0, %1, %2" : "=v"(v4) : "v"(rx[2][0]), "v"(rx[2][1]));
  asm("v_cvt_pk_bf16_f32 %0, %1, %2" : "=v"(v5) : "v"(rx[2][2]), "v"(rx[2][3]));
  asm("v_cvt_pk_bf16_f32 %0, %1, %2" : "=v"(v6) : "v"(rx[3][0]), "v"(rx[3][1]));
  asm("v_cvt_pk_bf16_f32 %0, %1, %2" : "=v"(v7) : "v"(rx[3][2]), "v"(rx[3][3]));
  uint4 a; a.x=v0; a.y=v1; a.z=v2; a.w=v3;
  uint4 b; b.x=v4; b.y=v5; b.z=v6; b.w=v7;
  *(uint4*)b0 = a;
  *(uint4*)b1 = b;
}

__global__ __launch_bounds__(256) void gemm_k(const float* __restrict__ xf,
    const float* __restrict__ wpf, const float* __restrict__ waf,
    float* __restrict__ phase0, float* __restrict__ amp0){
  __shared__ u16 lds[2][8192];          // [buf][16 KB]: A at 0, B at u16 4096
  const int tid = threadIdx.x;
  const int l   = tid & 63;
  const int w   = tid >> 6;

  // XCD-aware bijective swizzle: 704 blocks = 8 XCDs x 88; within an XCD,
  // 11 consecutive ranks share one A-tile (m0), iterating n0 -> L2 reuse.
  const int bid = blockIdx.x;
  const int s   = (bid & 7) * 88 + (bid >> 3);
  const int m0  = (s / 11) * 64;
  const int n0  = (s % 11) * 64;

  // staging map: thread -> row r = tid>>2 (0..63), col-quarter cq = tid&3 (16 f32)
  const int r  = tid >> 2;
  const int cq = tid & 3;
  const float* ga = xf + (size_t)(m0 + r) * N_DIMS + cq * 16;
  const int brow  = n0 + r;
  const float* gb = ((brow < N_OSC) ? wpf + (size_t)brow * N_DIMS
                                    : waf + (size_t)(brow - N_OSC) * N_DIMS) + cq * 16;
  // LDS write offsets (u16 units): slots (2cq+j) ^ (r&7), row stride 64 u16
  const int wa0 = r*64 + (((2*cq)   ^ (r&7)) * 8);
  const int wa1 = r*64 + (((2*cq+1) ^ (r&7)) * 8);

  f32x4 ra[4], rb[4];
  #define LD(kt) { \
    const float* pa = ga + (kt)*64; const float* pb = gb + (kt)*64; \
    ra[0]=*(const f32x4*)(pa);    ra[1]=*(const f32x4*)(pa+4); \
    ra[2]=*(const f32x4*)(pa+8);  ra[3]=*(const f32x4*)(pa+12); \
    rb[0]=*(const f32x4*)(pb);    rb[1]=*(const f32x4*)(pb+4); \
    rb[2]=*(const f32x4*)(pb+8);  rb[3]=*(const f32x4*)(pb+12); }
  #define WR(b) { \
    cvt_wr(ra, &lds[b][wa0],        &lds[b][wa1]); \
    cvt_wr(rb, &lds[b][4096 + wa0], &lds[b][4096 + wa1]); }

  // fragment read offsets (u16 units), swizzled to match
  const int rl = l & 15;
  const int q0 = l >> 4;
  const int wr = w >> 1, wc = w & 1;

  f32x4 acc[2][2] = {};
  LD(0)
  WR(0)
  LD(1)
  __syncthreads();

  for (int kt = 0; kt < 16; kt++){
    const int cb = kt & 1;
    s16x8 a[2][2], b[2][2];
    #pragma unroll
    for (int mi = 0; mi < 2; mi++)
    #pragma unroll
    for (int ks = 0; ks < 2; ks++){
      const int row = wr*32 + mi*16 + rl;
      a[mi][ks] = *(const s16x8*)&lds[cb][row*64 + (((ks*4 + q0) ^ (row&7)) * 8)];
    }
    #pragma unroll
    for (int nj = 0; nj < 2; nj++)
    #pragma unroll
    for (int ks = 0; ks < 2; ks++){
      const int row = wc*32 + nj*16 + rl;
      b[nj][ks] = *(const s16x8*)&lds[cb][4096 + row*64 + (((ks*4 + q0) ^ (row&7)) * 8)];
    }
    #pragma unroll
    for (int ks = 0; ks < 2; ks++)
    #pragma unroll
    for (int mi = 0; mi < 2; mi++)
    #pragma unroll
    for (int nj = 0; nj < 2; nj++)
      acc[mi][nj] = __builtin_amdgcn_mfma_f32_16x16x32_bf16(a[mi][ks], b[nj][ks], acc[mi][nj], 0,0,0);
    if (kt < 15){
      WR(cb^1)                 // tile kt+1 (regs), waits vmcnt for its loads only
      if (kt < 14) LD(kt+2)    // issue next loads after the waitcnt point
    }
    __syncthreads();
  }
  #undef LD
  #undef WR

  // C/D layout: col = lane&15, row = (lane>>4)*4 + reg
  #pragma unroll
  for (int mi = 0; mi < 2; mi++)
  #pragma unroll
  for (int nj = 0; nj < 2; nj++){
    const int n = n0 + wc*32 + nj*16 + rl;
    #pragma unroll
    for (int rg = 0; rg < 4; rg++){
      const int m = m0 + wr*32 + mi*16 + q0*4 + rg;
      float v = acc[mi][nj][rg];
      if (n < N_OSC) { float t = v * INV2PI; phase0[(size_t)m*N_OSC + n] = t - floorf(t); }
      else           { amp0[(size_t)m*N_OSC + (n - N_OSC)] = fmaxf(fabsf(v), EPSV); }
    }
  }
}

// ---------------- iteration kernel: packed-f16 rotation, DPP-only reduce ----------------
__device__ __forceinline__ int ibc(h2 v){ return __builtin_bit_cast(int, v); }
__device__ __forceinline__ h2  hbc(int v){ return __builtin_bit_cast(h2, v); }

__device__ __forceinline__ h2 rowsum16(h2 x){
  int v = ibc(x);
  v = ibc(hbc(v) + hbc(__builtin_amdgcn_mov_dpp(v, 0x121, 0xF, 0xF, true))); // row_ror:1
  v = ibc(hbc(v) + hbc(__builtin_amdgcn_mov_dpp(v, 0x122, 0xF, 0xF, true))); // row_ror:2
  v = ibc(hbc(v) + hbc(__builtin_amdgcn_mov_dpp(v, 0x124, 0xF, 0xF, true))); // row_ror:4
  v = ibc(hbc(v) + hbc(__builtin_amdgcn_mov_dpp(v, 0x128, 0xF, 0xF, true))); // row_ror:8
  return hbc(v);
}

__device__ __forceinline__ void updp(h2& s, h2& c, h2 cA, h2 sA, h2 GS, h2 GC){
  h2 e  = c*GS - s*GC;        // eps (radians), |e| <= 0.02
  h2 s1 = s*cA + c*sA;
  h2 c1 = c*cA - s*sA;
  s = s1 + c1*e;
  c = c1 - s1*e;
}

__device__ __forceinline__ h2 splat2(_Float16 v){ h2 r; r[0]=v; r[1]=v; return r; }

__global__ __launch_bounds__(256) void iter_k(const float* __restrict__ phase0,
                                              float* __restrict__ amp){
  const int tid = threadIdx.x;
  const int l   = tid & 63;
  const int g   = l & 15;
  const int row = blockIdx.x*16 + (tid>>6)*4 + (l>>4);
  const size_t rb = (size_t)row * N_OSC;

  const h2 cAd = splat2((_Float16)0.99211470f), sAd = splat2((_Float16)0.12533323f);
  const h2 cAt = splat2((_Float16)0.92977649f), sAt = splat2((_Float16)0.36812455f);
  const h2 cAg = splat2((_Float16)-0.80901699f), sAg = splat2((_Float16)0.58778525f);
  const h2 kd = splat2((_Float16)6.25e-4f);    // DT*COUPLING/32
  const h2 kt = splat2((_Float16)3.125e-4f);   // /64
  const h2 kg = splat2((_Float16)7.8125e-5f);  // /256

  h2 sD, cD, sT[2], cT[2], sG[8], cG[8];
  {
    const float* pr = phase0 + rb;
    #define SCP(dstS, dstC, idx, p0, p1) { \
      float a0 = (p0), a1 = (p1); \
      dstS[idx][0] = (_Float16)__builtin_amdgcn_sinf(a0); \
      dstS[idx][1] = (_Float16)__builtin_amdgcn_sinf(a1); \
      dstC[idx][0] = (_Float16)__builtin_amdgcn_cosf(a0); \
      dstC[idx][1] = (_Float16)__builtin_amdgcn_cosf(a1); }
    {
      float2 d = *(const float2*)(pr + 2*g);
      sD[0] = (_Float16)__builtin_amdgcn_sinf(d.x);
      sD[1] = (_Float16)__builtin_amdgcn_sinf(d.y);
      cD[0] = (_Float16)__builtin_amdgcn_cosf(d.x);
      cD[1] = (_Float16)__builtin_amdgcn_cosf(d.y);
    }
    {
      float4 t = *(const float4*)(pr + 32 + 4*g);
      SCP(sT, cT, 0, t.x, t.y) SCP(sT, cT, 1, t.z, t.w)
    }
    #pragma unroll
    for (int i = 0; i < 4; i++){
      float4 v = *(const float4*)(pr + 96 + 16*g + 4*i);
      SCP(sG, cG, 2*i,   v.x, v.y) SCP(sG, cG, 2*i+1, v.z, v.w)
    }
    #undef SCP
  }

  h2 PD, PT, PG;
  #define REDUCE { \
    h2 pd; pd[0] = sD[0]+sD[1]; pd[1] = cD[0]+cD[1]; \
    h2 ts = sT[0]+sT[1], tc = cT[0]+cT[1]; \
    h2 pt; pt[0] = ts[0]+ts[1]; pt[1] = tc[0]+tc[1]; \
    h2 gs = ((sG[0]+sG[1])+(sG[2]+sG[3]))+((sG[4]+sG[5])+(sG[6]+sG[7])); \
    h2 gc = ((cG[0]+cG[1])+(cG[2]+cG[3]))+((cG[4]+cG[5])+(cG[6]+cG[7])); \
    h2 pg; pg[0] = gs[0]+gs[1]; pg[1] = gc[0]+gc[1]; \
    PD = rowsum16(pd); PT = rowsum16(pt); PG = rowsum16(pg); }

  REDUCE

  float Pth = 1.f, Pga = 1.f, mPth = 1.f, mPga = 1.f;
  for (int t = 0; t < 32; t++){
    h2 gd = PD * kd, gt = PT * kt, gg = PG * kg;   // (k*S, k*C)
    h2 GSd = splat2(gd[0]), GCd = splat2(gd[1]);
    h2 GSt = splat2(gt[0]), GCt = splat2(gt[1]);
    h2 GSg = splat2(gg[0]), GCg = splat2(gg[1]);
    updp(sD, cD, cAd, sAd, GSd, GCd);
    updp(sT[0], cT[0], cAt, sAt, GSt, GCt);
    updp(sT[1], cT[1], cAt, sAt, GSt, GCt);
    #pragma unroll
    for (int i = 0; i < 8; i++) updp(sG[i], cG[i], cAg, sAg, GSg, GCg);
    REDUCE
    float Sd = (float)PD[0], Cd = (float)PD[1];
    float St = (float)PT[0], Ct = (float)PT[1];
    float ft = 1.f + 0.003f * Cd * __builtin_amdgcn_rsqf(Cd*Cd + Sd*Sd);
    float fg = 1.f + 0.003f * Ct * __builtin_amdgcn_rsqf(Ct*Ct + St*St);
    Pth *= ft; mPth = fminf(mPth, Pth);
    Pga *= fg; mPga = fminf(mPga, Pga);
  }
  #undef REDUCE

  const float cth = EPSV * Pth / mPth;
  const float cga = EPSV * Pga / mPga;
  {
    float4 a = *(const float4*)(amp + rb + 32 + 4*g);
    a.x = fmaxf(a.x*Pth, cth); a.y = fmaxf(a.y*Pth, cth);
    a.z = fmaxf(a.z*Pth, cth); a.w = fmaxf(a.w*Pth, cth);
    *(float4*)(amp + rb + 32 + 4*g) = a;
  }
  #pragma unroll
  for (int i = 0; i < 4; i++){
    float4 a = *(const float4*)(amp + rb + 96 + 16*g + 4*i);
    a.x = fmaxf(a.x*Pga, cga); a.y = fmaxf(a.y*Pga, cga);
    a.z = fmaxf(a.z*Pga, cga); a.w = fmaxf(a.w*Pga, cga);
    *(float4*)(amp + rb + 96 + 16*g + 4*i) = a;
  }
}

// ---------------- launch ----------------
extern "C" void kernel_launch(void* const* d_in, const int* in_sizes, int n_in,
                              void* d_out, int out_size, void* d_ws, size_t ws_size,
                              hipStream_t stream){
  const float* x  = (const float*)d_in[0];
  const float* wp = (const float*)d_in[1];
  const float* wa = (const float*)d_in[2];
  float* out = (float*)d_out;
  float* phase0 = (float*)d_ws;             // 5,767,168 B

  gemm_k<<<704, 256, 0, stream>>>(x, wp, wa, phase0, out);
  iter_k<<<256, 256, 0, stream>>>(phase0, out);
}

// Round 7
// 32.988 us; speedup vs baseline: 1.2101x; 1.2101x over previous
//
#include <hip/hip_runtime.h>

typedef float  f32x4 __attribute__((ext_vector_type(4)));
typedef short  s16x8 __attribute__((ext_vector_type(8)));
typedef _Float16 h2 __attribute__((ext_vector_type(2)));
typedef unsigned short u16;
typedef u16 u16x4 __attribute__((ext_vector_type(4)));

#define N_DIMS 1024
#define N_OSC  352
#define BATCH  4096
#define EPSV   1e-6f
#define INV2PI 0.15915494309189535f

// ---------------- conversion f32 -> bf16 ----------------
__device__ __forceinline__ u16 f2bf(float f){
  unsigned u = __builtin_bit_cast(unsigned, f);
  u += 0x7FFFu + ((u >> 16) & 1u);   // round-to-nearest-even
  return (u16)(u >> 16);
}

#define NX4 1048576   // 4096*1024/4
#define NW4 90112     // 352*1024/4 (per weight matrix)

// xb[4096][1024]; wb[704][1024] = W_phase rows then W_amp rows
__global__ __launch_bounds__(256) void convert_k(const f32x4* __restrict__ x,
    const f32x4* __restrict__ wp, const f32x4* __restrict__ wa,
    u16x4* __restrict__ xb, u16x4* __restrict__ wb){
  int i = blockIdx.x * 256 + threadIdx.x;
  f32x4 v; u16x4* dst;
  if (i < NX4) { v = x[i]; dst = xb + i; }
  else {
    int j = i - NX4;
    v = (j < NW4) ? wp[j] : wa[j - NW4];
    dst = wb + j;
  }
  u16x4 r;
  r[0]=f2bf(v[0]); r[1]=f2bf(v[1]); r[2]=f2bf(v[2]); r[3]=f2bf(v[3]);
  *dst = r;
}

// ---------------- GEMM: C[4096][704] = x @ [Wp;Wa]^T ----------------
// BM=BN=BK=64, 4 waves (2x2), wave tile 32x32 via 16x16x32 MFMA acc[2][2].
// LDS double-buffered 32 KB, global_load_lds width=16 staging, T2 swizzle via
// inverse-swizzled global source (rule #21).
// XCD-bijective block swizzle: 704 = 8 XCDs x 88; each XCD owns 8 contiguous
// m-tiles x all 11 n-tiles -> A (1 MB) + B (1.4 MB) L2-resident per XCD.
__device__ __forceinline__ void gload16(const u16* g, u16* l){
  __builtin_amdgcn_global_load_lds(
      (const __attribute__((address_space(1))) unsigned int*)(g),
      (__attribute__((address_space(3))) unsigned int*)(l), 16, 0, 0);
}

__global__ __launch_bounds__(256) void gemm_k(const u16* __restrict__ xb,
    const u16* __restrict__ wb, float* __restrict__ phase0, float* __restrict__ amp0){
  __shared__ u16 lds[2][8192];          // [buf][16 KB]: A at 0, B at u16 4096
  const int tid = threadIdx.x;
  const int l   = tid & 63;
  const int w   = tid >> 6;

  // HW maps consecutive blockIdx round-robin to XCDs (xcd = bid & 7).
  const int bid = blockIdx.x;
  const int xcd = bid & 7;
  const int r   = bid >> 3;             // 0..87 within this XCD
  const int mt  = xcd * 8 + r / 11;     // 8 contiguous m-tiles per XCD
  const int nt  = r % 11;
  const int m0  = mt * 64;
  const int n0  = nt * 64;

  const int srow = w*16 + (l >> 3);
  const int scol = (((l & 7) ^ (l >> 3)) * 8);      // inverse-swizzled k-slot
  const u16* ga = xb + (size_t)(m0 + srow) * N_DIMS + scol;
  const u16* gb = wb + (size_t)(n0 + srow) * N_DIMS + scol;

  #define STAGE(b, kt) { \
    const u16* gA = ga + (kt)*64; \
    const u16* gB = gb + (kt)*64; \
    gload16(gA,            &lds[b][w*1024]); \
    gload16(gA + 8*N_DIMS, &lds[b][w*1024 + 512]); \
    gload16(gB,            &lds[b][4096 + w*1024]); \
    gload16(gB + 8*N_DIMS, &lds[b][4096 + w*1024 + 512]); }

  const int rl = l & 15;
  const int q0 = l >> 4;
  const int sx = l & 7;
  const int wr = w >> 1, wc = w & 1;

  f32x4 acc[2][2] = {};
  STAGE(0, 0)
  __syncthreads();

  for (int kt = 0; kt < 16; kt++){
    const int cb = kt & 1;
    if (kt < 15) STAGE(cb^1, kt+1)
    s16x8 a[2][2], b[2][2];
    #pragma unroll
    for (int mi = 0; mi < 2; mi++)
    #pragma unroll
    for (int ks = 0; ks < 2; ks++){
      int off = (wr*32 + mi*16 + rl)*64 + (((ks*4 + q0) ^ sx) * 8);
      a[mi][ks] = *(const s16x8*)&lds[cb][off];
    }
    #pragma unroll
    for (int nj = 0; nj < 2; nj++)
    #pragma unroll
    for (int ks = 0; ks < 2; ks++){
      int off = 4096 + (wc*32 + nj*16 + rl)*64 + (((ks*4 + q0) ^ sx) * 8);
      b[nj][ks] = *(const s16x8*)&lds[cb][off];
    }
    #pragma unroll
    for (int ks = 0; ks < 2; ks++)
    #pragma unroll
    for (int mi = 0; mi < 2; mi++)
    #pragma unroll
    for (int nj = 0; nj < 2; nj++)
      acc[mi][nj] = __builtin_amdgcn_mfma_f32_16x16x32_bf16(a[mi][ks], b[nj][ks], acc[mi][nj], 0,0,0);
    __syncthreads();
  }
  #undef STAGE

  // C/D layout: col = lane&15, row = (lane>>4)*4 + reg
  #pragma unroll
  for (int mi = 0; mi < 2; mi++)
  #pragma unroll
  for (int nj = 0; nj < 2; nj++){
    const int n = n0 + wc*32 + nj*16 + rl;
    #pragma unroll
    for (int rg = 0; rg < 4; rg++){
      const int m = m0 + wr*32 + mi*16 + q0*4 + rg;
      float v = acc[mi][nj][rg];
      if (n < N_OSC) { float t = v * INV2PI; phase0[(size_t)m*N_OSC + n] = t - floorf(t); }
      else           { amp0[(size_t)m*N_OSC + (n - N_OSC)] = fmaxf(fabsf(v), EPSV); }
    }
  }
}

// ---------------- iteration kernel: packed-f16 rotation, DPP-only reduce ----------------
__device__ __forceinline__ int ibc(h2 v){ return __builtin_bit_cast(int, v); }
__device__ __forceinline__ h2  hbc(int v){ return __builtin_bit_cast(h2, v); }

__device__ __forceinline__ h2 rowsum16(h2 x){
  int v = ibc(x);
  v = ibc(hbc(v) + hbc(__builtin_amdgcn_mov_dpp(v, 0x121, 0xF, 0xF, true))); // row_ror:1
  v = ibc(hbc(v) + hbc(__builtin_amdgcn_mov_dpp(v, 0x122, 0xF, 0xF, true))); // row_ror:2
  v = ibc(hbc(v) + hbc(__builtin_amdgcn_mov_dpp(v, 0x124, 0xF, 0xF, true))); // row_ror:4
  v = ibc(hbc(v) + hbc(__builtin_amdgcn_mov_dpp(v, 0x128, 0xF, 0xF, true))); // row_ror:8
  return hbc(v);
}

__device__ __forceinline__ void updp(h2& s, h2& c, h2 cA, h2 sA, h2 GS, h2 GC){
  h2 e  = c*GS - s*GC;        // eps (radians), |e| <= 0.02
  h2 s1 = s*cA + c*sA;
  h2 c1 = c*cA - s*sA;
  s = s1 + c1*e;
  c = c1 - s1*e;
}

__device__ __forceinline__ h2 splat2(_Float16 v){ h2 r; r[0]=v; r[1]=v; return r; }

__global__ __launch_bounds__(256) void iter_k(const float* __restrict__ phase0,
                                              float* __restrict__ amp){
  const int tid = threadIdx.x;
  const int l   = tid & 63;
  const int g   = l & 15;
  const int row = blockIdx.x*16 + (tid>>6)*4 + (l>>4);
  const size_t rb = (size_t)row * N_OSC;

  const h2 cAd = splat2((_Float16)0.99211470f), sAd = splat2((_Float16)0.12533323f);
  const h2 cAt = splat2((_Float16)0.92977649f), sAt = splat2((_Float16)0.36812455f);
  const h2 cAg = splat2((_Float16)-0.80901699f), sAg = splat2((_Float16)0.58778525f);
  const h2 kd = splat2((_Float16)6.25e-4f);    // DT*COUPLING/32
  const h2 kt = splat2((_Float16)3.125e-4f);   // /64
  const h2 kg = splat2((_Float16)7.8125e-5f);  // /256

  h2 sD, cD, sT[2], cT[2], sG[8], cG[8];
  {
    const float* pr = phase0 + rb;
    #define SCP(dstS, dstC, idx, p0, p1) { \
      float a0 = (p0), a1 = (p1); \
      dstS[idx][0] = (_Float16)__builtin_amdgcn_sinf(a0); \
      dstS[idx][1] = (_Float16)__builtin_amdgcn_sinf(a1); \
      dstC[idx][0] = (_Float16)__builtin_amdgcn_cosf(a0); \
      dstC[idx][1] = (_Float16)__builtin_amdgcn_cosf(a1); }
    {
      float2 d = *(const float2*)(pr + 2*g);
      sD[0] = (_Float16)__builtin_amdgcn_sinf(d.x);
      sD[1] = (_Float16)__builtin_amdgcn_sinf(d.y);
      cD[0] = (_Float16)__builtin_amdgcn_cosf(d.x);
      cD[1] = (_Float16)__builtin_amdgcn_cosf(d.y);
    }
    {
      float4 t = *(const float4*)(pr + 32 + 4*g);
      SCP(sT, cT, 0, t.x, t.y) SCP(sT, cT, 1, t.z, t.w)
    }
    #pragma unroll
    for (int i = 0; i < 4; i++){
      float4 v = *(const float4*)(pr + 96 + 16*g + 4*i);
      SCP(sG, cG, 2*i,   v.x, v.y) SCP(sG, cG, 2*i+1, v.z, v.w)
    }
    #undef SCP
  }

  h2 PD, PT, PG;
  #define REDUCE { \
    h2 pd; pd[0] = sD[0]+sD[1]; pd[1] = cD[0]+cD[1]; \
    h2 ts = sT[0]+sT[1], tc = cT[0]+cT[1]; \
    h2 pt; pt[0] = ts[0]+ts[1]; pt[1] = tc[0]+tc[1]; \
    h2 gs = ((sG[0]+sG[1])+(sG[2]+sG[3]))+((sG[4]+sG[5])+(sG[6]+sG[7])); \
    h2 gc = ((cG[0]+cG[1])+(cG[2]+cG[3]))+((cG[4]+cG[5])+(cG[6]+cG[7])); \
    h2 pg; pg[0] = gs[0]+gs[1]; pg[1] = gc[0]+gc[1]; \
    PD = rowsum16(pd); PT = rowsum16(pt); PG = rowsum16(pg); }

  REDUCE

  float Pth = 1.f, Pga = 1.f, mPth = 1.f, mPga = 1.f;
  for (int t = 0; t < 32; t++){
    h2 gd = PD * kd, gt = PT * kt, gg = PG * kg;   // (k*S, k*C)
    h2 GSd = splat2(gd[0]), GCd = splat2(gd[1]);
    h2 GSt = splat2(gt[0]), GCt = splat2(gt[1]);
    h2 GSg = splat2(gg[0]), GCg = splat2(gg[1]);
    updp(sD, cD, cAd, sAd, GSd, GCd);
    updp(sT[0], cT[0], cAt, sAt, GSt, GCt);
    updp(sT[1], cT[1], cAt, sAt, GSt, GCt);
    #pragma unroll
    for (int i = 0; i < 8; i++) updp(sG[i], cG[i], cAg, sAg, GSg, GCg);
    REDUCE
    float Sd = (float)PD[0], Cd = (float)PD[1];
    float St = (float)PT[0], Ct = (float)PT[1];
    float ft = 1.f + 0.003f * Cd * __builtin_amdgcn_rsqf(Cd*Cd + Sd*Sd);
    float fg = 1.f + 0.003f * Ct * __builtin_amdgcn_rsqf(Ct*Ct + St*St);
    Pth *= ft; mPth = fminf(mPth, Pth);
    Pga *= fg; mPga = fminf(mPga, Pga);
  }
  #undef REDUCE

  const float cth = EPSV * Pth / mPth;
  const float cga = EPSV * Pga / mPga;
  {
    float4 a = *(const float4*)(amp + rb + 32 + 4*g);
    a.x = fmaxf(a.x*Pth, cth); a.y = fmaxf(a.y*Pth, cth);
    a.z = fmaxf(a.z*Pth, cth); a.w = fmaxf(a.w*Pth, cth);
    *(float4*)(amp + rb + 32 + 4*g) = a;
  }
  #pragma unroll
  for (int i = 0; i < 4; i++){
    float4 a = *(const float4*)(amp + rb + 96 + 16*g + 4*i);
    a.x = fmaxf(a.x*Pga, cga); a.y = fmaxf(a.y*Pga, cga);
    a.z = fmaxf(a.z*Pga, cga); a.w = fmaxf(a.w*Pga, cga);
    *(float4*)(amp + rb + 96 + 16*g + 4*i) = a;
  }
}

// ---------------- launch ----------------
extern "C" void kernel_launch(void* const* d_in, const int* in_sizes, int n_in,
                              void* d_out, int out_size, void* d_ws, size_t ws_size,
                              hipStream_t stream){
  const float* x  = (const float*)d_in[0];
  const float* wp = (const float*)d_in[1];
  const float* wa = (const float*)d_in[2];
  float* out = (float*)d_out;
  char* ws = (char*)d_ws;
  u16* xb  = (u16*)(ws);                    // 8,388,608 B
  u16* wb  = (u16*)(ws + 8388608);          // 1,441,792 B
  float* phase0 = (float*)(ws + 9830400);   // 5,767,168 B

  convert_k<<<4800, 256, 0, stream>>>((const f32x4*)x, (const f32x4*)wp, (const f32x4*)wa,
                                      (u16x4*)xb, (u16x4*)wb);
  gemm_k<<<704, 256, 0, stream>>>(xb, wb, phase0, out);
  iter_k<<<256, 256, 0, stream>>>(phase0, out);
}